// Round 7
// baseline (397.814 us; speedup 1.0000x reference)
//
#include <hip/hip_runtime.h>
#include <hip/hip_bf16.h>

// Single-head causal attention. fp32 in, fp32 out. B=4, T=4096, C=2048, HS=128.
//
// R7 = R6 with the wtr_kernel grid-axis bug fixed (R6 swapped c0/r0 roles ->
// OOB reads/writes -> garbage weights). Everything else identical to R6:
// fused one-pass QKV GEMM (x read once, N=384), W B-frags from global,
// V written transposed by epilogue, split-KV flash + merge (R5-proven).

#define B_  4
#define T_  4096
#define C_  2048
#define HS_ 128

typedef unsigned short u16;
typedef __attribute__((ext_vector_type(4))) short short4v;
typedef __attribute__((ext_vector_type(8))) short short8;
typedef __attribute__((ext_vector_type(4))) float floatx4;

static __device__ __forceinline__ u16 f2bf(float x) {
  union { float f; unsigned u; } c; c.f = x;
  unsigned r = 0x7fffu + ((c.u >> 16) & 1u);
  return (u16)((c.u + r) >> 16);
}

// ---------------------------------------------------------------- weight transpose
// Wq/Wk/Wv fp32 [C][HS] -> bf16 WT [3][HS][C]; grid (HS_/32, C_/32, 3).
// c0 spans HS (0..127), r0 spans C (0..2047) — R5-proven indexing.
__global__ __launch_bounds__(256) void wtr_kernel(
    const float* __restrict__ W0, const float* __restrict__ W1,
    const float* __restrict__ W2, u16* __restrict__ WT) {
  __shared__ u16 tile[32][33];
  int z = blockIdx.z;
  const float* src = (z == 0) ? W0 : (z == 1) ? W1 : W2;
  u16* dst = WT + (size_t)z * HS_ * C_;
  int c0 = blockIdx.x * 32, r0 = blockIdx.y * 32;
  int tx = threadIdx.x, ty = threadIdx.y;  // block (32, 8)
#pragma unroll
  for (int i = 0; i < 4; ++i)
    tile[ty + 8 * i][tx] = f2bf(src[(size_t)(r0 + ty + 8 * i) * HS_ + (c0 + tx)]);
  __syncthreads();
#pragma unroll
  for (int i = 0; i < 4; ++i)
    dst[(size_t)(c0 + ty + 8 * i) * C_ + (r0 + tx)] = tile[tx][ty + 8 * i];
}

// ---------------------------------------------------------------- fused QKV GEMM
// [16384 x 384] = bf16(X[16384 x 2048]) @ WT^T. BM=32, BK=32, 256 threads.
// Wave wv covers n-cols [wv*96, wv*96+96) as 6 n-frags; 2 m-frags (32 rows).
// Only X goes through LDS (converted fp32->bf16); W B-frags load from global.
// Epilogue: cols 0-127 -> q, 128-255 -> k, 256-383 -> vT[b][d][t] scatter.
#define GBM 32
#define GBK 32
#define XPAD 40  // row stride 80 B = 5*16 -> b128-aligned, 2-way banks (free)

__global__ __launch_bounds__(256) void qkv_fused_kernel(
    const float* __restrict__ X, const u16* __restrict__ WT3,
    u16* __restrict__ qv, u16* __restrict__ kv, u16* __restrict__ vT) {
  __shared__ u16 Xs[GBM][XPAD];
  int t = threadIdx.x;
  int wv = t >> 6, lane = t & 63, l15 = lane & 15, hi = lane >> 4;
  int wn = wv * 96;
  size_t mbase = (size_t)blockIdx.x * GBM;

  // staging map: thread t -> row m = t>>3, 4 elems at c4 = (t&7)*4
  int sm = t >> 3, sc = (t & 7) * 4;
  const float* xp = &X[(mbase + sm) * C_ + sc];

  floatx4 acc[2][6];
#pragma unroll
  for (int i = 0; i < 2; ++i)
#pragma unroll
    for (int j = 0; j < 6; ++j) acc[i][j] = (floatx4){0.f, 0.f, 0.f, 0.f};

  float4 xv = *(const float4*)xp;  // prefetch kt=0

  for (int kt = 0; kt < C_ / GBK; ++kt) {
    short4v xs;
    xs[0] = (short)f2bf(xv.x); xs[1] = (short)f2bf(xv.y);
    xs[2] = (short)f2bf(xv.z); xs[3] = (short)f2bf(xv.w);
    *(short4v*)&Xs[sm][sc] = xs;
    if (kt + 1 < C_ / GBK) xv = *(const float4*)(xp + (kt + 1) * GBK);
    __syncthreads();

    // B-frags from global: row = wn+nt*16+l15, k = kt*32 + hi*8 (16B loads)
    short8 bf[6];
#pragma unroll
    for (int nt = 0; nt < 6; ++nt)
      bf[nt] = *(const short8*)&WT3[(size_t)(wn + nt * 16 + l15) * C_ + kt * GBK + hi * 8];
    short8 af[2];
#pragma unroll
    for (int mt = 0; mt < 2; ++mt)
      af[mt] = *(const short8*)&Xs[mt * 16 + l15][hi * 8];
#pragma unroll
    for (int mt = 0; mt < 2; ++mt)
#pragma unroll
      for (int nt = 0; nt < 6; ++nt)
        acc[mt][nt] = __builtin_amdgcn_mfma_f32_16x16x32_bf16(
            af[mt], bf[nt], acc[mt][nt], 0, 0, 0);
    __syncthreads();
  }

  // epilogue: C/D layout col=lane&15, row=(lane>>4)*4+reg
#pragma unroll
  for (int nt = 0; nt < 6; ++nt) {
    int gcol = wn + nt * 16 + l15;
    int z = gcol >> 7, lcol = gcol & 127;
#pragma unroll
    for (int mt = 0; mt < 2; ++mt)
#pragma unroll
      for (int r = 0; r < 4; ++r) {
        size_t gt = mbase + mt * 16 + hi * 4 + r;  // global token row
        u16 val = f2bf(acc[mt][nt][r]);
        if (z == 0) {
          qv[gt * HS_ + lcol] = val;
        } else if (z == 1) {
          kv[gt * HS_ + lcol] = val;
        } else {
          size_t b = gt >> 12, tl = gt & (T_ - 1);
          vT[b * (size_t)(HS_ * T_) + (size_t)lcol * T_ + tl] = val;
        }
      }
  }
}

// ---------------------------------------------------------------- flash core (R5)
#define BQ 64
#define BKV 64
#define CHUNK 16  // KV tiles per split-KV block (1024 keys)

template <bool WRITE_PARTIAL>
static __device__ __forceinline__ void flash_body(
    const u16* __restrict__ q, const u16* __restrict__ k,
    const u16* __restrict__ vT, float* __restrict__ outO,
    float* __restrict__ Mp, float* __restrict__ Lp,
    int b, int qb, int kb0, int kb1, int slot) {
  __shared__ u16 Ks[BKV][136];
  __shared__ u16 Vs[HS_][72];
  __shared__ u16 Ps[BQ][72];
  int t = threadIdx.x;
  int wv = t >> 6, lane = t & 63, l15 = lane & 15, hi = lane >> 4;

  const float sc = 0.08838834764831845f * 1.4426950408889634f;

  short8 qf[4];
  {
    const u16* qrow = q + (size_t)(b * T_ + qb * BQ + wv * 16 + l15) * HS_;
#pragma unroll
    for (int ks = 0; ks < 4; ++ks)
      qf[ks] = *(const short8*)(qrow + ks * 32 + hi * 8);
  }

  floatx4 of[8];
#pragma unroll
  for (int dt = 0; dt < 8; ++dt) of[dt] = (floatx4){0.f, 0.f, 0.f, 0.f};
  float m_run[4], l_run[4];
#pragma unroll
  for (int r = 0; r < 4; ++r) { m_run[r] = -__builtin_inff(); l_run[r] = 0.f; }

  const u16* kbase = k + (size_t)b * T_ * HS_;
  const u16* vbase = vT + (size_t)b * HS_ * T_;

  for (int kb = kb0; kb <= kb1; ++kb) {
#pragma unroll
    for (int i = 0; i < 4; ++i) {
      int id = i * 256 + t;
      int n = id >> 4, c = id & 15;
      *(short8*)&Ks[n][c * 8] =
          *(const short8*)&kbase[(size_t)(kb * BKV + n) * HS_ + c * 8];
    }
#pragma unroll
    for (int i = 0; i < 4; ++i) {
      int id = i * 256 + t;
      int d = id >> 3, c = id & 7;
      *(short8*)&Vs[d][c * 8] =
          *(const short8*)&vbase[(size_t)d * T_ + kb * BKV + c * 8];
    }
    __syncthreads();

    floatx4 sf[4];
#pragma unroll
    for (int nt = 0; nt < 4; ++nt) {
      floatx4 s = (floatx4){0.f, 0.f, 0.f, 0.f};
#pragma unroll
      for (int ks = 0; ks < 4; ++ks) {
        short8 bfrag = *(const short8*)&Ks[nt * 16 + l15][ks * 32 + hi * 8];
        s = __builtin_amdgcn_mfma_f32_16x16x32_bf16(qf[ks], bfrag, s, 0, 0, 0);
      }
      sf[nt] = s;
    }

    float sv[4][4];
    if (kb == qb) {
#pragma unroll
      for (int nt = 0; nt < 4; ++nt) {
        int col = nt * 16 + l15;
#pragma unroll
        for (int r = 0; r < 4; ++r) {
          int row = wv * 16 + hi * 4 + r;
          sv[nt][r] = (col <= row) ? sf[nt][r] * sc : -__builtin_inff();
        }
      }
    } else {
#pragma unroll
      for (int nt = 0; nt < 4; ++nt)
#pragma unroll
        for (int r = 0; r < 4; ++r) sv[nt][r] = sf[nt][r] * sc;
    }

    float mt4[4], alpha[4];
#pragma unroll
    for (int r = 0; r < 4; ++r)
      mt4[r] = fmaxf(fmaxf(sv[0][r], sv[1][r]), fmaxf(sv[2][r], sv[3][r]));
#pragma unroll
    for (int off = 1; off < 16; off <<= 1)
#pragma unroll
      for (int r = 0; r < 4; ++r)
        mt4[r] = fmaxf(mt4[r], __shfl_xor(mt4[r], off));
#pragma unroll
    for (int r = 0; r < 4; ++r) {
      float mn = fmaxf(m_run[r], mt4[r]);
      alpha[r] = exp2f(m_run[r] - mn);
      m_run[r] = mn;
    }
    float pv[4][4], lt[4];
#pragma unroll
    for (int nt = 0; nt < 4; ++nt)
#pragma unroll
      for (int r = 0; r < 4; ++r) pv[nt][r] = exp2f(sv[nt][r] - m_run[r]);
#pragma unroll
    for (int r = 0; r < 4; ++r)
      lt[r] = (pv[0][r] + pv[1][r]) + (pv[2][r] + pv[3][r]);
#pragma unroll
    for (int off = 1; off < 16; off <<= 1)
#pragma unroll
      for (int r = 0; r < 4; ++r) lt[r] += __shfl_xor(lt[r], off);
#pragma unroll
    for (int r = 0; r < 4; ++r) l_run[r] = l_run[r] * alpha[r] + lt[r];
#pragma unroll
    for (int dt = 0; dt < 8; ++dt)
#pragma unroll
      for (int r = 0; r < 4; ++r) of[dt][r] *= alpha[r];

#pragma unroll
    for (int nt = 0; nt < 4; ++nt)
#pragma unroll
      for (int r = 0; r < 4; ++r)
        Ps[wv * 16 + hi * 4 + r][nt * 16 + l15] = f2bf(pv[nt][r]);
    __asm__ volatile("s_waitcnt lgkmcnt(0)" ::: "memory");

#pragma unroll
    for (int ks2 = 0; ks2 < 2; ++ks2) {
      short8 af = *(const short8*)&Ps[wv * 16 + l15][ks2 * 32 + hi * 8];
#pragma unroll
      for (int dt = 0; dt < 8; ++dt) {
        short8 bfrag = *(const short8*)&Vs[dt * 16 + l15][ks2 * 32 + hi * 8];
        of[dt] = __builtin_amdgcn_mfma_f32_16x16x32_bf16(af, bfrag, of[dt], 0, 0, 0);
      }
    }
    __syncthreads();
  }

  if (WRITE_PARTIAL) {
    float* Op = outO + (size_t)slot * (BQ * HS_);
#pragma unroll
    for (int dt = 0; dt < 8; ++dt)
#pragma unroll
      for (int r = 0; r < 4; ++r) {
        int row = wv * 16 + hi * 4 + r;
        Op[row * HS_ + dt * 16 + l15] = of[dt][r];
      }
    if (l15 == 0) {
#pragma unroll
      for (int r = 0; r < 4; ++r) {
        int row = wv * 16 + hi * 4 + r;
        Mp[slot * BQ + row] = m_run[r];
        Lp[slot * BQ + row] = l_run[r];
      }
    }
  } else {
    float rl[4];
#pragma unroll
    for (int r = 0; r < 4; ++r) rl[r] = 1.0f / l_run[r];
#pragma unroll
    for (int dt = 0; dt < 8; ++dt)
#pragma unroll
      for (int r = 0; r < 4; ++r) {
        size_t row = (size_t)(b * T_ + qb * BQ + wv * 16 + hi * 4 + r);
        outO[row * HS_ + dt * 16 + l15] = of[dt][r] * rl[r];
      }
  }
}

__global__ __launch_bounds__(256) void flash_partial_kernel(
    const u16* __restrict__ q, const u16* __restrict__ k,
    const u16* __restrict__ vT, float* __restrict__ Opart,
    float* __restrict__ Mpart, float* __restrict__ Lpart) {
  int qb = blockIdx.x, c = blockIdx.y, b = blockIdx.z;
  int kb0 = c * CHUNK;
  if (kb0 > qb) return;
  int kb1 = min(qb, kb0 + CHUNK - 1);
  int slot = (b * (T_ / BQ) + qb) * 4 + c;
  flash_body<true>(q, k, vT, Opart, Mpart, Lpart, b, qb, kb0, kb1, slot);
}

__global__ __launch_bounds__(256) void flash_attn_kernel(
    const u16* __restrict__ q, const u16* __restrict__ k,
    const u16* __restrict__ vT, float* __restrict__ out) {
  int qb = blockIdx.x, b = blockIdx.y;
  flash_body<false>(q, k, vT, out, nullptr, nullptr, b, qb, 0, qb, 0);
}

__global__ __launch_bounds__(256) void flash_merge_kernel(
    const float* __restrict__ Opart, const float* __restrict__ Mpart,
    const float* __restrict__ Lpart, float* __restrict__ out) {
  __shared__ float w[4][BQ];
  __shared__ float invL[BQ];
  int qb = blockIdx.x, b = blockIdx.y;
  int t = threadIdx.x;
  int nch = qb / CHUNK + 1;  // 1..4
  int slot0 = (b * (T_ / BQ) + qb) * 4;

  if (t < BQ) {
    float mv[4], mmax = -__builtin_inff();
    for (int c = 0; c < nch; ++c) {
      mv[c] = Mpart[(slot0 + c) * BQ + t];
      mmax = fmaxf(mmax, mv[c]);
    }
    float L = 0.f;
    for (int c = 0; c < nch; ++c) {
      float wc = exp2f(mv[c] - mmax);
      w[c][t] = wc;
      L += wc * Lpart[(slot0 + c) * BQ + t];
    }
    invL[t] = 1.0f / L;
  }
  __syncthreads();

  size_t obase = ((size_t)(b * T_) + (size_t)qb * BQ) * HS_;
#pragma unroll
  for (int j = 0; j < 32; ++j) {
    int e = j * 256 + t;  // 0..8191
    int row = e >> 7;
    float acc = 0.f;
    for (int c = 0; c < nch; ++c)
      acc += w[c][row] * Opart[(size_t)(slot0 + c) * (BQ * HS_) + e];
    out[obase + e] = acc * invL[row];
  }
}

// ---------------------------------------------------------------- launch
extern "C" void kernel_launch(void* const* d_in, const int* in_sizes, int n_in,
                              void* d_out, int out_size, void* d_ws, size_t ws_size,
                              hipStream_t stream) {
  const float* x  = (const float*)d_in[0];
  const float* Wq = (const float*)d_in[1];
  const float* Wk = (const float*)d_in[2];
  const float* Wv = (const float*)d_in[3];
  float* out = (float*)d_out;

  u16* ws = (u16*)d_ws;
  const size_t wtsz  = (size_t)HS_ * C_;       // 262144
  const size_t qkvsz = (size_t)B_ * T_ * HS_;  // 2097152
  u16* WT = ws;                 // [3][HS][C] bf16
  u16* qv = WT + 3 * wtsz;      // q [B*T][HS]
  u16* kv = qv + qkvsz;         // k [B*T][HS]
  u16* vT = kv + qkvsz;         // vT [B][HS][T]
  const size_t base_bytes = (3 * wtsz + 3 * qkvsz) * sizeof(u16);  // 14.2 MB

  const int NSLOT = B_ * (T_ / BQ) * 4;  // 1024
  float* Opart = (float*)((char*)d_ws + base_bytes);
  float* Mpart = Opart + (size_t)NSLOT * BQ * HS_;
  float* Lpart = Mpart + (size_t)NSLOT * BQ;
  const size_t split_bytes =
      base_bytes + ((size_t)NSLOT * BQ * HS_ + 2 * (size_t)NSLOT * BQ) * sizeof(float);

  wtr_kernel<<<dim3(HS_ / 32, C_ / 32, 3), dim3(32, 8), 0, stream>>>(Wq, Wk, Wv, WT);

  qkv_fused_kernel<<<(B_ * T_) / GBM, 256, 0, stream>>>(x, WT, qv, kv, vT);

  if (ws_size >= split_bytes) {
    flash_partial_kernel<<<dim3(T_ / BQ, 4, B_), 256, 0, stream>>>(
        qv, kv, vT, Opart, Mpart, Lpart);
    flash_merge_kernel<<<dim3(T_ / BQ, B_), 256, 0, stream>>>(
        Opart, Mpart, Lpart, out);
  } else {
    flash_attn_kernel<<<dim3(T_ / BQ, B_), 256, 0, stream>>>(qv, kv, vT, out);
  }
}